// Round 2
// baseline (117.231 us; speedup 1.0000x reference)
//
#include <hip/hip_runtime.h>

constexpr int TPB   = 256;
constexpr int ITEMS = 32;
constexpr int TILE  = TPB * ITEMS;   // 8192 elements per block
constexpr int GRID  = 977;           // 977*8192 = 8,003,584 >= 8,000,000
constexpr unsigned MAGIC = 0xC0DE600Du;   // != 0xAAAAAAAA ws-poison, != 0
constexpr int NPAIR = TILE / 2;              // 4096 float4s (= d-pairs) per block
constexpr int SLOTS = NPAIR + (NPAIR >> 4); // pad 1 float2 per 16 pairs -> 4352

// native 4-float vector for __builtin_nontemporal_* (HIP float4 is a class
// type the builtin rejects; this is layout-identical).
typedef float fx4 __attribute__((ext_vector_type(4)));

// Clamp monoid: f(x) = min(max(x + A, B), C). compose(l, r) (l applied first):
//   A = Al + Ar;  B = max(Bl + Ar, Br);  C = min(max(Cl + Ar, Br), Cr)
// Affine monoid: f(x) = P*x + Q. compose(l, r): P = Pl*Pr; Q = Pr*Ql + Qr.
//
// R12 = R11 with NT builtins routed through ext_vector_type (compile fix).
// R11 changes vs R10 (structure identical otherwise):
//  * Coalesced memory path via LDS staging. Per-lane 256B-contiguous ownership
//    made every VMEM instr 64x16B at 256B (loads) / 128B (stores) stride ->
//    64 distinct 64B lines per instr (4x transaction inflation). Now:
//    global->LDS coalesced NT float4 loads (subtract on the fly), padded
//    float2 layout (write 4-way conflict = 1.58x [m136], per-thread read
//    2-way = free), and the mirror for stores (row write free, coalesced
//    NT float4 store).
//  * p == k^32 for every full thread: hoisted out of the phase-C loop,
//    scan seeded with it (saves 32 v_mul per thread).
//  * lane-0 exact fix-up shrunk to [0,32): tid1 is saturated on the fast
//    path so its only error is B-start damped by k^32 <= 1.1e-5 (k<0.7),
//    180x under the 2e-3 tolerance; staged stores skip m<8 (elements [0,32)).
// Deadlock-freedom unchanged: waits target only lower blockIdx, dispatch is
// ascending, and 977 blocks at 4/CU (LDS 34.9KB/block -> still 4/CU) are
// fully co-resident.

#define AT_LOAD(p)    __hip_atomic_load((p), __ATOMIC_RELAXED, __HIP_MEMORY_SCOPE_AGENT)
#define AT_STORE(p,v) __hip_atomic_store((p), (v), __ATOMIC_RELAXED, __HIP_MEMORY_SCOPE_AGENT)

__global__ __launch_bounds__(TPB, 4)
void awbm_kernel(const float* __restrict__ x,
                 const float* __restrict__ pBFI,
                 const float* __restrict__ pK,
                 const float* __restrict__ pSmax,
                 float* __restrict__ out,
                 float* __restrict__ ws,
                 int T)
{
    __shared__ float2 sd[SLOTS];  // staged d-pairs, then staged results
    __shared__ float sm3[12];     // phase-A wave aggregates (3 x 4 waves)
    __shared__ float sm2[8];      // phase-C wave aggregates (2 x 4 waves)
    __shared__ float bc[2];       // fallback broadcast: S / B at block start

    const int tid  = threadIdx.x;
    const int lane = tid & 63;
    const int wv   = tid >> 6;
    const int b    = blockIdx.x;
    const int gbase = b * TILE;
    const int toff  = tid * ITEMS;
    const bool full = (gbase + toff) < T;      // all-or-nothing (divisibility)

    // ---- coalesced stage: global -> LDS (d = precip - evap) ----
    {
        const int nf4   = T >> 1;              // total float4s in x
        const int fbase = gbase >> 1;          // block's first float4
        const fx4* x4 = (const fx4*)x;
#pragma unroll
        for (int i = 0; i < 16; ++i) {
            int f = i * TPB + tid;             // coalesced: lane-contiguous
            if (fbase + f < nf4) {
                fx4 v = __builtin_nontemporal_load(&x4[fbase + f]);
                sd[f + (f >> 4)] = make_float2(v.x - v.y, v.z - v.w);
            }
        }
    }
    __syncthreads();   // B0

    // per-thread contiguous read-back (2-way bank alias = free)
    float d[ITEMS];
    if (full) {
        const float2* row = &sd[17 * tid];     // 16 pairs + 1 pad per row
#pragma unroll
        for (int j = 0; j < 16; ++j) {
            float2 pr = row[j];
            d[2 * j] = pr.x; d[2 * j + 1] = pr.y;
        }
    }

    float*    scrA = ws;
    float*    scrB = ws + GRID;
    float*    scrC = ws + 2 * GRID;
    float*    scrP = ws + 3 * GRID;
    float*    scrQ = ws + 4 * GRID;
    unsigned* f1   = (unsigned*)(ws + 5 * GRID);
    unsigned* f2   = (unsigned*)(ws + 6 * GRID);

    const float bfi  = pBFI[0];
    const float k    = pK[0];
    const float smax = pSmax[0];
    const float omb  = 1.0f - bfi;
    const float omk  = 1.0f - k;
    const float INF  = __builtin_inff();
    const float k2 = k * k, k4 = k2 * k2, k8 = k4 * k4, k16 = k8 * k8;
    const float k32 = k16 * k16;               // per-full-thread affine P

    // ---- Phase A: per-thread clamp fold (identity if empty) ----
    float rA = 0.f, rB = -INF, rC = INF;
    if (full) {
#pragma unroll
        for (int j = 0; j < ITEMS; ++j) {
            float dd = d[j];
            rA += dd;
            rB = fmaxf(rB + dd, 0.f);
            rC = fminf(fmaxf(rC + dd, 0.f), smax);
        }
    }
#pragma unroll
    for (int s = 1; s < 64; s <<= 1) {
        float pA = __shfl_up(rA, s, 64), pB = __shfl_up(rB, s, 64), pC = __shfl_up(rC, s, 64);
        if (lane >= s) {
            float nA = pA + rA, nB = fmaxf(pB + rA, rB), nC = fminf(fmaxf(pC + rA, rB), rC);
            rA = nA; rB = nB; rC = nC;
        }
    }
    if (lane == 63) { sm3[wv * 3] = rA; sm3[wv * 3 + 1] = rB; sm3[wv * 3 + 2] = rC; }
    __syncthreads();   // B1
    float wA = 0.f, wB = -INF, wC = INF;       // exclusive cross-wave prefix
    for (int i = 0; i < wv; ++i) {
        float a = sm3[i * 3], bb = sm3[i * 3 + 1], c = sm3[i * 3 + 2];
        float nA = wA + a, nB = fmaxf(wB + a, bb), nC = fminf(fmaxf(wC + a, bb), c);
        wA = nA; wB = nB; wC = nC;
    }
    {   // thread inclusive across block
        float nA = wA + rA, nB = fmaxf(wB + rA, rB), nC = fminf(fmaxf(wC + rA, rB), rC);
        rA = nA; rB = nB; rC = nC;
    }
    if (tid == TPB - 1) {                      // publish1: exact, gate-free
        AT_STORE(&scrA[b], rA); AT_STORE(&scrB[b], rB); AT_STORE(&scrC[b], rC);
        __atomic_signal_fence(__ATOMIC_SEQ_CST);
        __builtin_amdgcn_s_waitcnt(0);
        __atomic_signal_fence(__ATOMIC_SEQ_CST);
        AT_STORE(&f1[b], MAGIC);
    }
    float eA, eB, eC;                          // thread-exclusive prefix map
    {
        float pA = __shfl_up(rA, 1, 64), pB = __shfl_up(rB, 1, 64), pC = __shfl_up(rC, 1, 64);
        eA = (lane == 0) ? wA : pA;
        eB = (lane == 0) ? wB : pB;
        eC = (lane == 0) ? wC : pC;
    }

    // ---- fast/fallback decision (B2) ----
    int bad = (full && tid > 0 && eB < eC) ? 1 : 0;
    int cnt = __syncthreads_count(bad);
    const bool fallback = (cnt != 0) || !(k > 0.0f && k < 0.70f) || (T - gbase < 64);

    if (!fallback) {
        // ================= FAST PATH (gate-free throughput) =================
        float S = fminf(fmaxf(0.5f + eA, eB), eC);   // exact for saturated threads
        float c = 0.f;
        if (full) {
#pragma unroll
            for (int j = 0; j < ITEMS; ++j) {
                float dd = d[j];
                float S1 = fmaxf(S + dd, 0.f);
                float ex = fmaxf(S1 - smax, 0.f);
                S = S1 - ex;
                float w = c + bfi * ex;
                d[j] = omb * ex + omk * w;
                c = k * w;
            }
        }
        float p = full ? k32 : 1.f;            // hoisted: P = k^ITEMS, constant
#pragma unroll
        for (int s = 1; s < 64; s <<= 1) {
            float pp = __shfl_up(p, s, 64), pc = __shfl_up(c, s, 64);
            if (lane >= s) {
                float nq = p * pc + c;
                p = pp * p;
                c = nq;
            }
        }
        if (lane == 63) { sm2[wv * 2] = p; sm2[wv * 2 + 1] = c; }
        __syncthreads();   // B3
        float wP = 1.f, wQ = 0.f;
        for (int i = 0; i < wv; ++i) {
            float gp = sm2[i * 2], gq = sm2[i * 2 + 1];
            wQ = gp * wQ + gq;
            wP = wP * gp;
        }
        {
            float nq = p * wQ + c;
            p = wP * p;
            c = nq;
        }
        if (tid == TPB - 1) {                  // publish2: exact to <1e-35, gate-free
            AT_STORE(&scrP[b], p); AT_STORE(&scrQ[b], c);
            __atomic_signal_fence(__ATOMIC_SEQ_CST);
            __builtin_amdgcn_s_waitcnt(0);
            __atomic_signal_fence(__ATOMIC_SEQ_CST);
            AT_STORE(&f2[b], MAGIC);
        }
        float eP, eQ;
        {
            float pp = __shfl_up(p, 1, 64), pc = __shfl_up(c, 1, 64);
            eP = (lane == 0) ? wP : pp;
            eQ = (lane == 0) ? wQ : pc;
        }

        // speculative epilogue in registers, then stage results to LDS rows
        if (full) {
            float Bst = eP * 1.0f + eQ;        // guess B_blockstart=1; err <= k^(32*tid)
            float f = omk * Bst;
#pragma unroll
            for (int j = 0; j < ITEMS; ++j) { d[j] += f; f *= k; }
            float2* row = &sd[17 * tid];       // 2-way bank alias = free
#pragma unroll
            for (int j = 0; j < 16; ++j) row[j] = make_float2(d[2 * j], d[2 * j + 1]);
        }
        __syncthreads();   // B4

        // coalesced NT store; skip m<8 (elements [0,32), lane-0 writes exact)
        {
            const int obase4 = gbase >> 2;
            const int no4    = T >> 2;
            fx4* o4 = (fx4*)out;
#pragma unroll
            for (int i = 0; i < 8; ++i) {
                int m = i * TPB + tid;         // coalesced float4 index
                if (m >= 8 && obase4 + m < no4) {
                    int s0 = 2 * m + ((2 * m) >> 4);   // pairs 2m,2m+1 never split by pad
                    float2 a = sd[s0], e = sd[s0 + 1];
                    fx4 v; v.x = a.x; v.y = a.y; v.z = e.x; v.w = e.y;
                    __builtin_nontemporal_store(v, &o4[obase4 + m]);
                }
            }
        }

        // lane-0 fix-up: both 1-hop gates + exact serial recompute of [0,32)
        if (tid == 0) {
            float Sst;
            if (b == 0) Sst = 0.5f;
            else {
                float aA = 0.f, aB = -INF, aC = INF;
                int j = b - 1;
                for (;;) {
                    if (j < 0) { Sst = fminf(fmaxf(0.5f + aA, aB), aC); break; }
                    while (AT_LOAD(&f1[j]) != MAGIC) __builtin_amdgcn_s_sleep(1);
                    __atomic_signal_fence(__ATOMIC_ACQUIRE);
                    float Aj = AT_LOAD(&scrA[j]), Bj = AT_LOAD(&scrB[j]), Cj = AT_LOAD(&scrC[j]);
                    float nA = Aj + aA, nB = fmaxf(Bj + aA, aB), nC = fminf(fmaxf(Cj + aA, aB), aC);
                    aA = nA; aB = nB; aC = nC;
                    if (aB >= aC) { Sst = aC; break; }
                    --j;
                }
            }
            float Bcur;
            if (b == 0) Bcur = 1.0f;
            else {
                float accP = 1.f, Bacc = 0.f;
                int j = b - 1;
                for (;;) {
                    if (j < 0) { Bacc += accP * 1.0f; break; }
                    if (accP < 1e-35f) break;
                    while (AT_LOAD(&f2[j]) != MAGIC) __builtin_amdgcn_s_sleep(1);
                    __atomic_signal_fence(__ATOMIC_ACQUIRE);
                    float Pj = AT_LOAD(&scrP[j]), Qj = AT_LOAD(&scrQ[j]);
                    Bacc += accP * Qj;
                    accP *= Pj;
                    --j;
                }
                Bcur = Bacc;
            }
            // exact recompute of elements [gbase, gbase+32)
            const float4* xf = (const float4*)x + ((long)gbase >> 1);
            float4 vv[16];
#pragma unroll
            for (int u = 0; u < 16; ++u) vv[u] = xf[u];
            float Sc = Sst;
            float o[32];
#pragma unroll
            for (int j = 0; j < 32; ++j) {
                float dd = (j & 1) ? (vv[j >> 1].z - vv[j >> 1].w)
                                   : (vv[j >> 1].x - vv[j >> 1].y);
                float S1 = fmaxf(Sc + dd, 0.f);
                float ex = fmaxf(S1 - smax, 0.f);
                Sc = S1 - ex;
                Bcur += bfi * ex;
                float bf = omk * Bcur;
                Bcur -= bf;
                o[j] = omb * ex + bf;
            }
            fx4* o4 = (fx4*)out + ((long)gbase >> 2);
#pragma unroll
            for (int u = 0; u < 8; ++u) {
                fx4 v; v.x = o[4 * u]; v.y = o[4 * u + 1]; v.z = o[4 * u + 2]; v.w = o[4 * u + 3];
                __builtin_nontemporal_store(v, &o4[u]);
            }
        }
    } else {
        // ================= FALLBACK (exact R9 path) =================
        if (tid == 0) {
            float aA = 0.f, aB = -INF, aC = INF;
            float Sst;
            int j = b - 1;
            for (;;) {
                if (j < 0) { Sst = fminf(fmaxf(0.5f + aA, aB), aC); break; }
                while (AT_LOAD(&f1[j]) != MAGIC) __builtin_amdgcn_s_sleep(1);
                __atomic_signal_fence(__ATOMIC_ACQUIRE);
                float Aj = AT_LOAD(&scrA[j]), Bj = AT_LOAD(&scrB[j]), Cj = AT_LOAD(&scrC[j]);
                float nA = Aj + aA, nB = fmaxf(Bj + aA, aB), nC = fminf(fmaxf(Cj + aA, aB), aC);
                aA = nA; aB = nB; aC = nC;
                if (aB >= aC) { Sst = aC; break; }
                --j;
            }
            bc[0] = Sst;
        }
        __syncthreads();
        float S = fminf(fmaxf(bc[0] + eA, eB), eC);
        float c = 0.f;
        if (full) {
#pragma unroll
            for (int j = 0; j < ITEMS; ++j) {
                float dd = d[j];
                float S1 = fmaxf(S + dd, 0.f);
                float ex = fmaxf(S1 - smax, 0.f);
                S = S1 - ex;
                float w = c + bfi * ex;
                d[j] = omb * ex + omk * w;
                c = k * w;
            }
        }
        float p = full ? k32 : 1.f;
#pragma unroll
        for (int s = 1; s < 64; s <<= 1) {
            float pp = __shfl_up(p, s, 64), pc = __shfl_up(c, s, 64);
            if (lane >= s) {
                float nq = p * pc + c;
                p = pp * p;
                c = nq;
            }
        }
        if (lane == 63) { sm2[wv * 2] = p; sm2[wv * 2 + 1] = c; }
        __syncthreads();
        float wP = 1.f, wQ = 0.f;
        for (int i = 0; i < wv; ++i) {
            float gp = sm2[i * 2], gq = sm2[i * 2 + 1];
            wQ = gp * wQ + gq;
            wP = wP * gp;
        }
        {
            float nq = p * wQ + c;
            p = wP * p;
            c = nq;
        }
        if (tid == TPB - 1) {
            AT_STORE(&scrP[b], p); AT_STORE(&scrQ[b], c);
            __atomic_signal_fence(__ATOMIC_SEQ_CST);
            __builtin_amdgcn_s_waitcnt(0);
            __atomic_signal_fence(__ATOMIC_SEQ_CST);
            AT_STORE(&f2[b], MAGIC);
        }
        float eP, eQ;
        {
            float pp = __shfl_up(p, 1, 64), pc = __shfl_up(c, 1, 64);
            eP = (lane == 0) ? wP : pp;
            eQ = (lane == 0) ? wQ : pc;
        }
        if (tid == 0) {
            float accP = 1.f, Bst = 0.f;
            int j = b - 1;
            for (;;) {
                if (j < 0) { Bst += accP * 1.0f; break; }
                if (accP < 1e-35f) break;
                while (AT_LOAD(&f2[j]) != MAGIC) __builtin_amdgcn_s_sleep(1);
                __atomic_signal_fence(__ATOMIC_ACQUIRE);
                float Pj = AT_LOAD(&scrP[j]), Qj = AT_LOAD(&scrQ[j]);
                Bst  += accP * Qj;
                accP *= Pj;
                --j;
            }
            bc[1] = Bst;
        }
        __syncthreads();
        float Bst = eP * bc[1] + eQ;
        if (full) {
            float f = omk * Bst;
#pragma unroll
            for (int j = 0; j < ITEMS; ++j) { d[j] += f; f *= k; }
            float4* o4 = (float4*)out + ((long)(gbase + toff) >> 2);
#pragma unroll
            for (int u = 0; u < 8; ++u)
                o4[u] = make_float4(d[4 * u], d[4 * u + 1], d[4 * u + 2], d[4 * u + 3]);
        }
    }
}

extern "C" void kernel_launch(void* const* d_in, const int* in_sizes, int n_in,
                              void* d_out, int out_size, void* d_ws, size_t ws_size,
                              hipStream_t stream) {
    const float* x    = (const float*)d_in[0];
    const float* BFI  = (const float*)d_in[1];
    const float* K    = (const float*)d_in[2];
    const float* Smax = (const float*)d_in[3];
    float* out = (float*)d_out;
    float* ws  = (float*)d_ws;   // needs ~27.4 KB; 0xAA poison = "not ready" for flags
    int T = out_size;            // 8,000,000

    awbm_kernel<<<dim3(GRID), dim3(TPB), 0, stream>>>(x, BFI, K, Smax, out, ws, T);
}

// Round 3
// 116.274 us; speedup vs baseline: 1.0082x; 1.0082x over previous
//
#include <hip/hip_runtime.h>

constexpr int TPB   = 256;
constexpr int ITEMS = 32;
constexpr int TILE  = TPB * ITEMS;   // 8192 elements per block
constexpr int GRID  = 977;           // 977*8192 = 8,003,584 >= 8,000,000
constexpr unsigned MAGIC = 0xC0DE600Du;   // != 0xAAAAAAAA ws-poison, != 0
constexpr int NPAIR = TILE / 2;              // 4096 float4s (= d-pairs) per block
constexpr int SLOTS = NPAIR + (NPAIR >> 4); // pad 1 float2 per 16 pairs -> 4352

// native 4-float vector for __builtin_nontemporal_* (HIP float4 is a class
// type the builtin rejects; this is layout-identical).
typedef float fx4 __attribute__((ext_vector_type(4)));

// Clamp monoid: f(x) = min(max(x + A, B), C). compose(l, r) (l applied first):
//   A = Al + Ar;  B = max(Bl + Ar, Br);  C = min(max(Cl + Ar, Br), Cr)
// Affine monoid: f(x) = P*x + Q. compose(l, r): P = Pl*Pr; Q = Pr*Ql + Qr.
//
// R13 changes vs R12: WAVE-LOCAL staging, both directions.
//  * Wave w owns input float4s [1024w,1024w+1024) and output float4s
//    [512w,512w+512) of its block tile. Staging producer==consumer wave, so
//    the LDS handoff needs only `s_waitcnt lgkmcnt(0)` (lockstep wave: all
//    lanes' ds_writes are issued before the wait executes) — NO barrier.
//    B0 and B4 from R12 are deleted (5 -> 3 barriers). Each wave starts
//    folding as soon as ITS 16 loads land (no slowest-wave gate), and each
//    wave's stores issue without waiting for other waves' epilogues.
//  * Same padded LDS layout: write 4-way conflict (1.58x, 16 ops), row
//    read/write 2-way (free). Regions per wave are disjoint; input-row reads
//    precede result-row writes in each lane's program order => no hazards.
//  * Everything else identical to R12 (gate-free publishes, speculative
//    epilogue, lane-0 exact [0,32) fixup, fallback path).
// Deadlock-freedom unchanged: waits target only lower blockIdx, dispatch is
// ascending, and 977 blocks at 4/CU (LDS 34.9KB/block -> 4/CU) are fully
// co-resident.

#define AT_LOAD(p)    __hip_atomic_load((p), __ATOMIC_RELAXED, __HIP_MEMORY_SCOPE_AGENT)
#define AT_STORE(p,v) __hip_atomic_store((p), (v), __ATOMIC_RELAXED, __HIP_MEMORY_SCOPE_AGENT)
#define WAVE_LDS_FENCE() asm volatile("s_waitcnt lgkmcnt(0)" ::: "memory")

__global__ __launch_bounds__(TPB, 4)
void awbm_kernel(const float* __restrict__ x,
                 const float* __restrict__ pBFI,
                 const float* __restrict__ pK,
                 const float* __restrict__ pSmax,
                 float* __restrict__ out,
                 float* __restrict__ ws,
                 int T)
{
    __shared__ float2 sd[SLOTS];  // staged d-pairs, then staged results
    __shared__ float sm3[12];     // phase-A wave aggregates (3 x 4 waves)
    __shared__ float sm2[8];      // phase-C wave aggregates (2 x 4 waves)
    __shared__ float bc[2];       // fallback broadcast: S / B at block start

    const int tid  = threadIdx.x;
    const int lane = tid & 63;
    const int wv   = tid >> 6;
    const int b    = blockIdx.x;
    const int gbase = b * TILE;
    const int toff  = tid * ITEMS;
    const bool full = (gbase + toff) < T;      // all-or-nothing (divisibility)

    // ---- wave-local coalesced stage: global -> LDS (d = precip - evap) ----
    {
        const int nf4   = T >> 1;              // total float4s in x
        const int fbase = gbase >> 1;          // block's first float4
        const fx4* x4 = (const fx4*)x;
#pragma unroll
        for (int i = 0; i < 16; ++i) {
            int f = (wv << 10) + i * 64 + lane;   // wave-contiguous 1KiB/instr
            if (fbase + f < nf4) {
                fx4 v = __builtin_nontemporal_load(&x4[fbase + f]);
                sd[f + (f >> 4)] = make_float2(v.x - v.y, v.z - v.w);
            }
        }
    }
    WAVE_LDS_FENCE();   // same-wave producer/consumer: no barrier needed

    // per-thread contiguous read-back (2-way bank alias = free)
    float d[ITEMS];
    if (full) {
        const float2* row = &sd[17 * tid];     // 16 pairs + 1 pad per row
#pragma unroll
        for (int j = 0; j < 16; ++j) {
            float2 pr = row[j];
            d[2 * j] = pr.x; d[2 * j + 1] = pr.y;
        }
    }

    float*    scrA = ws;
    float*    scrB = ws + GRID;
    float*    scrC = ws + 2 * GRID;
    float*    scrP = ws + 3 * GRID;
    float*    scrQ = ws + 4 * GRID;
    unsigned* f1   = (unsigned*)(ws + 5 * GRID);
    unsigned* f2   = (unsigned*)(ws + 6 * GRID);

    const float bfi  = pBFI[0];
    const float k    = pK[0];
    const float smax = pSmax[0];
    const float omb  = 1.0f - bfi;
    const float omk  = 1.0f - k;
    const float INF  = __builtin_inff();
    const float k2 = k * k, k4 = k2 * k2, k8 = k4 * k4, k16 = k8 * k8;
    const float k32 = k16 * k16;               // per-full-thread affine P

    // ---- Phase A: per-thread clamp fold (identity if empty) ----
    float rA = 0.f, rB = -INF, rC = INF;
    if (full) {
#pragma unroll
        for (int j = 0; j < ITEMS; ++j) {
            float dd = d[j];
            rA += dd;
            rB = fmaxf(rB + dd, 0.f);
            rC = fminf(fmaxf(rC + dd, 0.f), smax);
        }
    }
#pragma unroll
    for (int s = 1; s < 64; s <<= 1) {
        float pA = __shfl_up(rA, s, 64), pB = __shfl_up(rB, s, 64), pC = __shfl_up(rC, s, 64);
        if (lane >= s) {
            float nA = pA + rA, nB = fmaxf(pB + rA, rB), nC = fminf(fmaxf(pC + rA, rB), rC);
            rA = nA; rB = nB; rC = nC;
        }
    }
    if (lane == 63) { sm3[wv * 3] = rA; sm3[wv * 3 + 1] = rB; sm3[wv * 3 + 2] = rC; }
    __syncthreads();   // B1
    float wA = 0.f, wB = -INF, wC = INF;       // exclusive cross-wave prefix
    for (int i = 0; i < wv; ++i) {
        float a = sm3[i * 3], bb = sm3[i * 3 + 1], c = sm3[i * 3 + 2];
        float nA = wA + a, nB = fmaxf(wB + a, bb), nC = fminf(fmaxf(wC + a, bb), c);
        wA = nA; wB = nB; wC = nC;
    }
    {   // thread inclusive across block
        float nA = wA + rA, nB = fmaxf(wB + rA, rB), nC = fminf(fmaxf(wC + rA, rB), rC);
        rA = nA; rB = nB; rC = nC;
    }
    if (tid == TPB - 1) {                      // publish1: exact, gate-free
        AT_STORE(&scrA[b], rA); AT_STORE(&scrB[b], rB); AT_STORE(&scrC[b], rC);
        __atomic_signal_fence(__ATOMIC_SEQ_CST);
        __builtin_amdgcn_s_waitcnt(0);
        __atomic_signal_fence(__ATOMIC_SEQ_CST);
        AT_STORE(&f1[b], MAGIC);
    }
    float eA, eB, eC;                          // thread-exclusive prefix map
    {
        float pA = __shfl_up(rA, 1, 64), pB = __shfl_up(rB, 1, 64), pC = __shfl_up(rC, 1, 64);
        eA = (lane == 0) ? wA : pA;
        eB = (lane == 0) ? wB : pB;
        eC = (lane == 0) ? wC : pC;
    }

    // ---- fast/fallback decision (B2) ----
    int bad = (full && tid > 0 && eB < eC) ? 1 : 0;
    int cnt = __syncthreads_count(bad);
    const bool fallback = (cnt != 0) || !(k > 0.0f && k < 0.70f) || (T - gbase < 64);

    if (!fallback) {
        // ================= FAST PATH (gate-free throughput) =================
        float S = fminf(fmaxf(0.5f + eA, eB), eC);   // exact for saturated threads
        float c = 0.f;
        if (full) {
#pragma unroll
            for (int j = 0; j < ITEMS; ++j) {
                float dd = d[j];
                float S1 = fmaxf(S + dd, 0.f);
                float ex = fmaxf(S1 - smax, 0.f);
                S = S1 - ex;
                float w = c + bfi * ex;
                d[j] = omb * ex + omk * w;
                c = k * w;
            }
        }
        float p = full ? k32 : 1.f;            // hoisted: P = k^ITEMS, constant
#pragma unroll
        for (int s = 1; s < 64; s <<= 1) {
            float pp = __shfl_up(p, s, 64), pc = __shfl_up(c, s, 64);
            if (lane >= s) {
                float nq = p * pc + c;
                p = pp * p;
                c = nq;
            }
        }
        if (lane == 63) { sm2[wv * 2] = p; sm2[wv * 2 + 1] = c; }
        __syncthreads();   // B3
        float wP = 1.f, wQ = 0.f;
        for (int i = 0; i < wv; ++i) {
            float gp = sm2[i * 2], gq = sm2[i * 2 + 1];
            wQ = gp * wQ + gq;
            wP = wP * gp;
        }
        {
            float nq = p * wQ + c;
            p = wP * p;
            c = nq;
        }
        if (tid == TPB - 1) {                  // publish2: exact to <1e-35, gate-free
            AT_STORE(&scrP[b], p); AT_STORE(&scrQ[b], c);
            __atomic_signal_fence(__ATOMIC_SEQ_CST);
            __builtin_amdgcn_s_waitcnt(0);
            __atomic_signal_fence(__ATOMIC_SEQ_CST);
            AT_STORE(&f2[b], MAGIC);
        }
        float eP, eQ;
        {
            float pp = __shfl_up(p, 1, 64), pc = __shfl_up(c, 1, 64);
            eP = (lane == 0) ? wP : pp;
            eQ = (lane == 0) ? wQ : pc;
        }

        // speculative epilogue in registers, then stage results to LDS rows
        if (full) {
            float Bst = eP * 1.0f + eQ;        // guess B_blockstart=1; err <= k^(32*tid)
            float f = omk * Bst;
#pragma unroll
            for (int j = 0; j < ITEMS; ++j) { d[j] += f; f *= k; }
            float2* row = &sd[17 * tid];       // 2-way bank alias = free
#pragma unroll
            for (int j = 0; j < 16; ++j) row[j] = make_float2(d[2 * j], d[2 * j + 1]);
        }
        WAVE_LDS_FENCE();   // same-wave handoff: no barrier

        // wave-local coalesced NT store; skip m<8 ([0,32), lane-0 writes exact)
        {
            const int obase4 = gbase >> 2;
            const int no4    = T >> 2;
            fx4* o4 = (fx4*)out;
#pragma unroll
            for (int i = 0; i < 8; ++i) {
                int m = (wv << 9) + i * 64 + lane;   // wave-contiguous float4s
                if (m >= 8 && obase4 + m < no4) {
                    int s0 = 2 * m + ((2 * m) >> 4);   // pairs 2m,2m+1 never split by pad
                    float2 a = sd[s0], e = sd[s0 + 1];
                    fx4 v; v.x = a.x; v.y = a.y; v.z = e.x; v.w = e.y;
                    __builtin_nontemporal_store(v, &o4[obase4 + m]);
                }
            }
        }

        // lane-0 fix-up: both 1-hop gates + exact serial recompute of [0,32)
        if (tid == 0) {
            float Sst;
            if (b == 0) Sst = 0.5f;
            else {
                float aA = 0.f, aB = -INF, aC = INF;
                int j = b - 1;
                for (;;) {
                    if (j < 0) { Sst = fminf(fmaxf(0.5f + aA, aB), aC); break; }
                    while (AT_LOAD(&f1[j]) != MAGIC) __builtin_amdgcn_s_sleep(1);
                    __atomic_signal_fence(__ATOMIC_ACQUIRE);
                    float Aj = AT_LOAD(&scrA[j]), Bj = AT_LOAD(&scrB[j]), Cj = AT_LOAD(&scrC[j]);
                    float nA = Aj + aA, nB = fmaxf(Bj + aA, aB), nC = fminf(fmaxf(Cj + aA, aB), aC);
                    aA = nA; aB = nB; aC = nC;
                    if (aB >= aC) { Sst = aC; break; }
                    --j;
                }
            }
            float Bcur;
            if (b == 0) Bcur = 1.0f;
            else {
                float accP = 1.f, Bacc = 0.f;
                int j = b - 1;
                for (;;) {
                    if (j < 0) { Bacc += accP * 1.0f; break; }
                    if (accP < 1e-35f) break;
                    while (AT_LOAD(&f2[j]) != MAGIC) __builtin_amdgcn_s_sleep(1);
                    __atomic_signal_fence(__ATOMIC_ACQUIRE);
                    float Pj = AT_LOAD(&scrP[j]), Qj = AT_LOAD(&scrQ[j]);
                    Bacc += accP * Qj;
                    accP *= Pj;
                    --j;
                }
                Bcur = Bacc;
            }
            // exact recompute of elements [gbase, gbase+32)
            const float4* xf = (const float4*)x + ((long)gbase >> 1);
            float4 vv[16];
#pragma unroll
            for (int u = 0; u < 16; ++u) vv[u] = xf[u];
            float Sc = Sst;
            float o[32];
#pragma unroll
            for (int j = 0; j < 32; ++j) {
                float dd = (j & 1) ? (vv[j >> 1].z - vv[j >> 1].w)
                                   : (vv[j >> 1].x - vv[j >> 1].y);
                float S1 = fmaxf(Sc + dd, 0.f);
                float ex = fmaxf(S1 - smax, 0.f);
                Sc = S1 - ex;
                Bcur += bfi * ex;
                float bf = omk * Bcur;
                Bcur -= bf;
                o[j] = omb * ex + bf;
            }
            fx4* o4 = (fx4*)out + ((long)gbase >> 2);
#pragma unroll
            for (int u = 0; u < 8; ++u) {
                fx4 v; v.x = o[4 * u]; v.y = o[4 * u + 1]; v.z = o[4 * u + 2]; v.w = o[4 * u + 3];
                __builtin_nontemporal_store(v, &o4[u]);
            }
        }
    } else {
        // ================= FALLBACK (exact R9 path) =================
        if (tid == 0) {
            float aA = 0.f, aB = -INF, aC = INF;
            float Sst;
            int j = b - 1;
            for (;;) {
                if (j < 0) { Sst = fminf(fmaxf(0.5f + aA, aB), aC); break; }
                while (AT_LOAD(&f1[j]) != MAGIC) __builtin_amdgcn_s_sleep(1);
                __atomic_signal_fence(__ATOMIC_ACQUIRE);
                float Aj = AT_LOAD(&scrA[j]), Bj = AT_LOAD(&scrB[j]), Cj = AT_LOAD(&scrC[j]);
                float nA = Aj + aA, nB = fmaxf(Bj + aA, aB), nC = fminf(fmaxf(Cj + aA, aB), aC);
                aA = nA; aB = nB; aC = nC;
                if (aB >= aC) { Sst = aC; break; }
                --j;
            }
            bc[0] = Sst;
        }
        __syncthreads();
        float S = fminf(fmaxf(bc[0] + eA, eB), eC);
        float c = 0.f;
        if (full) {
#pragma unroll
            for (int j = 0; j < ITEMS; ++j) {
                float dd = d[j];
                float S1 = fmaxf(S + dd, 0.f);
                float ex = fmaxf(S1 - smax, 0.f);
                S = S1 - ex;
                float w = c + bfi * ex;
                d[j] = omb * ex + omk * w;
                c = k * w;
            }
        }
        float p = full ? k32 : 1.f;
#pragma unroll
        for (int s = 1; s < 64; s <<= 1) {
            float pp = __shfl_up(p, s, 64), pc = __shfl_up(c, s, 64);
            if (lane >= s) {
                float nq = p * pc + c;
                p = pp * p;
                c = nq;
            }
        }
        if (lane == 63) { sm2[wv * 2] = p; sm2[wv * 2 + 1] = c; }
        __syncthreads();
        float wP = 1.f, wQ = 0.f;
        for (int i = 0; i < wv; ++i) {
            float gp = sm2[i * 2], gq = sm2[i * 2 + 1];
            wQ = gp * wQ + gq;
            wP = wP * gp;
        }
        {
            float nq = p * wQ + c;
            p = wP * p;
            c = nq;
        }
        if (tid == TPB - 1) {
            AT_STORE(&scrP[b], p); AT_STORE(&scrQ[b], c);
            __atomic_signal_fence(__ATOMIC_SEQ_CST);
            __builtin_amdgcn_s_waitcnt(0);
            __atomic_signal_fence(__ATOMIC_SEQ_CST);
            AT_STORE(&f2[b], MAGIC);
        }
        float eP, eQ;
        {
            float pp = __shfl_up(p, 1, 64), pc = __shfl_up(c, 1, 64);
            eP = (lane == 0) ? wP : pp;
            eQ = (lane == 0) ? wQ : pc;
        }
        if (tid == 0) {
            float accP = 1.f, Bst = 0.f;
            int j = b - 1;
            for (;;) {
                if (j < 0) { Bst += accP * 1.0f; break; }
                if (accP < 1e-35f) break;
                while (AT_LOAD(&f2[j]) != MAGIC) __builtin_amdgcn_s_sleep(1);
                __atomic_signal_fence(__ATOMIC_ACQUIRE);
                float Pj = AT_LOAD(&scrP[j]), Qj = AT_LOAD(&scrQ[j]);
                Bst  += accP * Qj;
                accP *= Pj;
                --j;
            }
            bc[1] = Bst;
        }
        __syncthreads();
        float Bst = eP * bc[1] + eQ;
        if (full) {
            float f = omk * Bst;
#pragma unroll
            for (int j = 0; j < ITEMS; ++j) { d[j] += f; f *= k; }
            float4* o4 = (float4*)out + ((long)(gbase + toff) >> 2);
#pragma unroll
            for (int u = 0; u < 8; ++u)
                o4[u] = make_float4(d[4 * u], d[4 * u + 1], d[4 * u + 2], d[4 * u + 3]);
        }
    }
}

extern "C" void kernel_launch(void* const* d_in, const int* in_sizes, int n_in,
                              void* d_out, int out_size, void* d_ws, size_t ws_size,
                              hipStream_t stream) {
    const float* x    = (const float*)d_in[0];
    const float* BFI  = (const float*)d_in[1];
    const float* K    = (const float*)d_in[2];
    const float* Smax = (const float*)d_in[3];
    float* out = (float*)d_out;
    float* ws  = (float*)d_ws;   // needs ~27.4 KB; 0xAA poison = "not ready" for flags
    int T = out_size;            // 8,000,000

    awbm_kernel<<<dim3(GRID), dim3(TPB), 0, stream>>>(x, BFI, K, Smax, out, ws, T);
}